// Round 2
// baseline (3488.430 us; speedup 1.0000x reference)
//
#include <hip/hip_runtime.h>
#include <hip/hip_bf16.h>

#define SEQ   4096
#define NB    2
#define NH    16
#define HD    128
#define TOPK  128
#define MDIM  (NB*SEQ)     // 8192
#define NDIM  2048
#define KDIM  2048

// ---------------------------------------------------------------------------
// GEMM (NT): C[M,N] = A[M,Kd] @ W[N,Kd]^T
// 128x128 block tile, BK=16, 256 threads, 8x8 per-thread accumulators.
// ---------------------------------------------------------------------------
__global__ __launch_bounds__(256) void gemm_nt(const float* __restrict__ A,
                                               const float* __restrict__ W,
                                               float* __restrict__ C,
                                               int N, int Kd)
{
    __shared__ float As[16][128];   // [k][m]
    __shared__ float Bs[16][128];   // [k][n]
    const int t  = threadIdx.x;
    const int tx = t & 15, ty = t >> 4;
    const int bm = blockIdx.x, bn = blockIdx.y;
    const int lr = t >> 1;            // staging row 0..127
    const int lc = (t & 1) * 8;       // staging col 0 or 8
    const float* Ap = A + (long)(bm * 128 + lr) * Kd + lc;
    const float* Wp = W + (long)(bn * 128 + lr) * Kd + lc;

    float acc[8][8];
#pragma unroll
    for (int i = 0; i < 8; ++i)
#pragma unroll
        for (int j = 0; j < 8; ++j) acc[i][j] = 0.f;

    for (int k0 = 0; k0 < Kd; k0 += 16) {
        float4 a0 = *(const float4*)(Ap + k0);
        float4 a1 = *(const float4*)(Ap + k0 + 4);
        float4 b0 = *(const float4*)(Wp + k0);
        float4 b1 = *(const float4*)(Wp + k0 + 4);
        __syncthreads();   // previous tile's reads done before overwrite
        As[lc+0][lr] = a0.x; As[lc+1][lr] = a0.y; As[lc+2][lr] = a0.z; As[lc+3][lr] = a0.w;
        As[lc+4][lr] = a1.x; As[lc+5][lr] = a1.y; As[lc+6][lr] = a1.z; As[lc+7][lr] = a1.w;
        Bs[lc+0][lr] = b0.x; Bs[lc+1][lr] = b0.y; Bs[lc+2][lr] = b0.z; Bs[lc+3][lr] = b0.w;
        Bs[lc+4][lr] = b1.x; Bs[lc+5][lr] = b1.y; Bs[lc+6][lr] = b1.z; Bs[lc+7][lr] = b1.w;
        __syncthreads();
#pragma unroll
        for (int kk = 0; kk < 16; ++kk) {
            float a[8], b[8];
            *(float4*)&a[0] = *(const float4*)&As[kk][ty * 8];
            *(float4*)&a[4] = *(const float4*)&As[kk][ty * 8 + 4];
            *(float4*)&b[0] = *(const float4*)&Bs[kk][tx * 8];
            *(float4*)&b[4] = *(const float4*)&Bs[kk][tx * 8 + 4];
#pragma unroll
            for (int i = 0; i < 8; ++i)
#pragma unroll
                for (int j = 0; j < 8; ++j)
                    acc[i][j] = fmaf(a[i], b[j], acc[i][j]);
        }
    }

#pragma unroll
    for (int i = 0; i < 8; ++i) {
        float* Cp = C + (long)(bm * 128 + ty * 8 + i) * N + bn * 128 + tx * 8;
        *(float4*)&Cp[0] = make_float4(acc[i][0], acc[i][1], acc[i][2], acc[i][3]);
        *(float4*)&Cp[4] = make_float4(acc[i][4], acc[i][5], acc[i][6], acc[i][7]);
    }
}

// ---------------------------------------------------------------------------
// Fused score net: per 128-row tile of Kflat[131072][128], compute
// hidden = relu(Krows @ sw1^T + sb1) in registers, contract with sw2,
// write scores[(b*NH+h)*SEQ + s]. No 64MB intermediate.
// ---------------------------------------------------------------------------
__global__ __launch_bounds__(256) void scorenet(const float* __restrict__ Kb,
                                                const float* __restrict__ sw1,
                                                const float* __restrict__ sb1,
                                                const float* __restrict__ sw2,
                                                const float* __restrict__ sb2,
                                                float* __restrict__ scores)
{
    __shared__ float As[16][128];
    __shared__ float Bs[16][128];
    __shared__ float red[128][17];
    const int t  = threadIdx.x;
    const int tx = t & 15, ty = t >> 4;
    const int bm = blockIdx.x;
    const int lr = t >> 1;
    const int lc = (t & 1) * 8;
    const float* Ap = Kb + (long)(bm * 128 + lr) * HD + lc;
    const float* Wp = sw1 + lr * HD + lc;

    float acc[8][8];
#pragma unroll
    for (int i = 0; i < 8; ++i)
#pragma unroll
        for (int j = 0; j < 8; ++j) acc[i][j] = 0.f;

    for (int k0 = 0; k0 < HD; k0 += 16) {
        float4 a0 = *(const float4*)(Ap + k0);
        float4 a1 = *(const float4*)(Ap + k0 + 4);
        float4 b0 = *(const float4*)(Wp + k0);
        float4 b1 = *(const float4*)(Wp + k0 + 4);
        __syncthreads();
        As[lc+0][lr] = a0.x; As[lc+1][lr] = a0.y; As[lc+2][lr] = a0.z; As[lc+3][lr] = a0.w;
        As[lc+4][lr] = a1.x; As[lc+5][lr] = a1.y; As[lc+6][lr] = a1.z; As[lc+7][lr] = a1.w;
        Bs[lc+0][lr] = b0.x; Bs[lc+1][lr] = b0.y; Bs[lc+2][lr] = b0.z; Bs[lc+3][lr] = b0.w;
        Bs[lc+4][lr] = b1.x; Bs[lc+5][lr] = b1.y; Bs[lc+6][lr] = b1.z; Bs[lc+7][lr] = b1.w;
        __syncthreads();
#pragma unroll
        for (int kk = 0; kk < 16; ++kk) {
            float a[8], b[8];
            *(float4*)&a[0] = *(const float4*)&As[kk][ty * 8];
            *(float4*)&a[4] = *(const float4*)&As[kk][ty * 8 + 4];
            *(float4*)&b[0] = *(const float4*)&Bs[kk][tx * 8];
            *(float4*)&b[4] = *(const float4*)&Bs[kk][tx * 8 + 4];
#pragma unroll
            for (int i = 0; i < 8; ++i)
#pragma unroll
                for (int j = 0; j < 8; ++j)
                    acc[i][j] = fmaf(a[i], b[j], acc[i][j]);
        }
    }

    // epilogue: bias + relu + dot with sw2 along hidden dim, reduce across tx
    float b1v[8], w2v[8];
#pragma unroll
    for (int j = 0; j < 8; ++j) {
        b1v[j] = sb1[tx * 8 + j];
        w2v[j] = sw2[tx * 8 + j];
    }
#pragma unroll
    for (int i = 0; i < 8; ++i) {
        float p = 0.f;
#pragma unroll
        for (int j = 0; j < 8; ++j)
            p += fmaxf(acc[i][j] + b1v[j], 0.f) * w2v[j];
        red[ty * 8 + i][tx] = p;
    }
    __syncthreads();
    if (t < 128) {
        float s = sb2[0];
#pragma unroll
        for (int c = 0; c < 16; ++c) s += red[t][c];
        long r = (long)bm * 128 + t;               // r = (b*SEQ+s_idx)*NH + h
        int b  = (int)(r >> 16);
        int si = (int)((r >> 4) & (SEQ - 1));
        int h  = (int)(r & (NH - 1));
        scores[((b * NH + h) << 12) + si] = s;
    }
}

// ---------------------------------------------------------------------------
// Exact top-128 per (b,h) via 8-bit radix select on order-preserving uint keys.
// Ties at the threshold key take lowest indices (matches jax.lax.top_k set).
// ---------------------------------------------------------------------------
__global__ __launch_bounds__(256) void topk_sel(const float* __restrict__ scores,
                                                int* __restrict__ sel)
{
    __shared__ unsigned keys[SEQ];
    __shared__ unsigned hist[256];
    __shared__ int scal2[2];
    __shared__ unsigned cntG;
    __shared__ unsigned short tpre[256];
    const int t  = threadIdx.x;
    const int bh = blockIdx.x;
    const float* sc = scores + (long)bh * SEQ;
    for (int i = t; i < SEQ; i += 256) {
        unsigned u = __float_as_uint(sc[i]);
        u = (u & 0x80000000u) ? ~u : (u | 0x80000000u);
        keys[i] = u;
    }
    unsigned prefix = 0;
    int rem = TOPK;
    const int i0 = t * 16;
    for (int shift = 24; shift >= 0; shift -= 8) {
        hist[t] = 0;
        __syncthreads();
        const unsigned pm = (shift == 24) ? 0u : (0xFFFFFFFFu << (shift + 8));
        for (int i = i0; i < i0 + 16; ++i) {
            unsigned k = keys[i];
            if (((k ^ prefix) & pm) == 0) atomicAdd(&hist[(k >> shift) & 255], 1u);
        }
        __syncthreads();
        if (t == 0) {
            int r = rem, chosen = 0;
            for (int b = 255; b >= 0; --b) {
                int c = (int)hist[b];
                if (c >= r) { chosen = b; break; }
                r -= c;
            }
            scal2[0] = chosen; scal2[1] = r;
        }
        __syncthreads();
        prefix |= ((unsigned)scal2[0]) << shift;
        rem = scal2[1];
        __syncthreads();
    }
    if (t == 0) cntG = 0;
    __syncthreads();
    const unsigned T = prefix;
    int myT = 0;
    for (int i = i0; i < i0 + 16; ++i) {
        unsigned k = keys[i];
        if (k > T) {
            unsigned p = atomicAdd(&cntG, 1u);
            sel[bh * TOPK + p] = i;
        } else if (k == T) myT++;
    }
    tpre[t] = (unsigned short)myT;
    __syncthreads();
    if (t == 0) {
        unsigned s = 0;
        for (int i = 0; i < 256; ++i) { unsigned c = tpre[i]; tpre[i] = (unsigned short)s; s += c; }
    }
    __syncthreads();
    const int base = TOPK - rem;
    int rank = tpre[t];
    for (int i = i0; i < i0 + 16; ++i) {
        if (keys[i] == T) {
            if (rank < rem) sel[bh * TOPK + base + rank] = i;
            rank++;
        }
    }
}

// ---------------------------------------------------------------------------
// Gather selected K/V rows into contiguous [bh][128][128]
// ---------------------------------------------------------------------------
__global__ void gather_kv(const float* __restrict__ Kb, const float* __restrict__ Vb,
                          const int* __restrict__ sel,
                          float* __restrict__ ks, float* __restrict__ vs)
{
    int bh = blockIdx.x >> 7;
    int j  = blockIdx.x & 127;
    int d  = threadIdx.x;
    int s  = sel[bh * TOPK + j];
    int b = bh >> 4, h = bh & (NH - 1);
    long src = ((long)(b * SEQ + s)) * NDIM + h * HD + d;
    ks[((long)bh * TOPK + j) * HD + d] = Kb[src];
    vs[((long)bh * TOPK + j) * HD + d] = Vb[src];
}

// ---------------------------------------------------------------------------
// Attention over 128 selected keys. Block = 32 queries of one (b,h).
// ---------------------------------------------------------------------------
__global__ __launch_bounds__(256) void attention(const float* __restrict__ Qb,
                                                 const float* __restrict__ ks,
                                                 const float* __restrict__ vs,
                                                 float* __restrict__ outp)
{
    __shared__ float qs[32][132];   // +4 pad: row stride 132 breaks 128-stride bank aliasing
    __shared__ float sc[32][132];
    __shared__ float kv[32][132];
    const int bh = blockIdx.x;
    const int qt = blockIdx.y;
    const int b = bh >> 4, h = bh & (NH - 1);
    const int t = threadIdx.x;
    const int q0 = qt * 32;
    const float scale = 0.08838834764831845f;   // 1/sqrt(128)

    const float* qbase = Qb + ((long)(b * SEQ + q0)) * NDIM + h * HD;
    for (int f = t; f < 1024; f += 256) {
        int qi = f >> 5, c = f & 31;
        *(float4*)&qs[qi][c * 4] = *(const float4*)(qbase + (long)qi * NDIM + c * 4);
    }
    const float* kbase = ks + (long)bh * TOPK * HD;
    const float* vbase = vs + (long)bh * TOPK * HD;
    const int kj = t & 31, qg = t >> 5;
    for (int ch = 0; ch < 4; ++ch) {
        __syncthreads();
        for (int f = t; f < 1024; f += 256) {
            int j = f >> 5, c = f & 31;
            *(float4*)&kv[j][c * 4] = *(const float4*)(kbase + (ch * 32 + j) * HD + c * 4);
        }
        __syncthreads();
        float a0 = 0.f, a1 = 0.f, a2 = 0.f, a3 = 0.f;
        for (int d4 = 0; d4 < 32; ++d4) {
            float4 kk4 = *(const float4*)&kv[kj][d4 * 4];
            float4 q0v = *(const float4*)&qs[qg * 4 + 0][d4 * 4];
            float4 q1v = *(const float4*)&qs[qg * 4 + 1][d4 * 4];
            float4 q2v = *(const float4*)&qs[qg * 4 + 2][d4 * 4];
            float4 q3v = *(const float4*)&qs[qg * 4 + 3][d4 * 4];
            a0 = fmaf(q0v.x, kk4.x, fmaf(q0v.y, kk4.y, fmaf(q0v.z, kk4.z, fmaf(q0v.w, kk4.w, a0))));
            a1 = fmaf(q1v.x, kk4.x, fmaf(q1v.y, kk4.y, fmaf(q1v.z, kk4.z, fmaf(q1v.w, kk4.w, a1))));
            a2 = fmaf(q2v.x, kk4.x, fmaf(q2v.y, kk4.y, fmaf(q2v.z, kk4.z, fmaf(q2v.w, kk4.w, a2))));
            a3 = fmaf(q3v.x, kk4.x, fmaf(q3v.y, kk4.y, fmaf(q3v.z, kk4.z, fmaf(q3v.w, kk4.w, a3))));
        }
        sc[qg * 4 + 0][ch * 32 + kj] = a0;
        sc[qg * 4 + 1][ch * 32 + kj] = a1;
        sc[qg * 4 + 2][ch * 32 + kj] = a2;
        sc[qg * 4 + 3][ch * 32 + kj] = a3;
    }
    __syncthreads();
    if (t < 32) {
        float mx = -1e30f;
        for (int j = 0; j < 128; ++j) mx = fmaxf(mx, sc[t][j]);
        float sum = 0.f;
        for (int j = 0; j < 128; ++j) {
            float e = __expf((sc[t][j] - mx) * scale);
            sc[t][j] = e; sum += e;
        }
        float inv = 1.f / sum;
        for (int j = 0; j < 128; ++j) sc[t][j] *= inv;
    }
    const int qi = t >> 3, dg = t & 7;
    float acc[16];
#pragma unroll
    for (int i = 0; i < 16; ++i) acc[i] = 0.f;
    for (int ch = 0; ch < 4; ++ch) {
        __syncthreads();
        for (int f = t; f < 1024; f += 256) {
            int j = f >> 5, c = f & 31;
            *(float4*)&kv[j][c * 4] = *(const float4*)(vbase + (ch * 32 + j) * HD + c * 4);
        }
        __syncthreads();
        for (int j = 0; j < 32; ++j) {
            float a = sc[qi][ch * 32 + j];
#pragma unroll
            for (int i4 = 0; i4 < 4; ++i4) {
                float4 vv = *(const float4*)&kv[j][dg * 16 + i4 * 4];
                acc[i4 * 4 + 0] = fmaf(a, vv.x, acc[i4 * 4 + 0]);
                acc[i4 * 4 + 1] = fmaf(a, vv.y, acc[i4 * 4 + 1]);
                acc[i4 * 4 + 2] = fmaf(a, vv.z, acc[i4 * 4 + 2]);
                acc[i4 * 4 + 3] = fmaf(a, vv.w, acc[i4 * 4 + 3]);
            }
        }
    }
    float* o = outp + ((long)(b * SEQ + q0 + qi)) * NDIM + h * HD + dg * 16;
#pragma unroll
    for (int i4 = 0; i4 < 4; ++i4)
        *(float4*)(o + i4 * 4) = make_float4(acc[i4 * 4 + 0], acc[i4 * 4 + 1],
                                             acc[i4 * 4 + 2], acc[i4 * 4 + 3]);
}

// ---------------------------------------------------------------------------
extern "C" void kernel_launch(void* const* d_in, const int* in_sizes, int n_in,
                              void* d_out, int out_size, void* d_ws, size_t ws_size,
                              hipStream_t stream)
{
    const float* x   = (const float*)d_in[0];
    const float* wq  = (const float*)d_in[1];
    const float* wk  = (const float*)d_in[2];
    const float* wv  = (const float*)d_in[3];
    const float* wo  = (const float*)d_in[4];
    const float* sw1 = (const float*)d_in[5];
    const float* sb1 = (const float*)d_in[6];
    const float* sw2 = (const float*)d_in[7];
    const float* sb2 = (const float*)d_in[8];
    float* out = (float*)d_out;

    // workspace (floats): Q | K | V(->attn out) | scores | sel | ksel | vsel
    // total = 3*16777216 + 131072 + 4096 + 2*524288 = 51,515,392 floats (196.5 MiB)
    float* ws   = (float*)d_ws;
    const long PROJ = (long)MDIM * NDIM;        // 16,777,216 floats
    float* Q       = ws;
    float* Kb      = Q  + PROJ;
    float* Vb      = Kb + PROJ;
    float* scoresB = Vb + PROJ;                 // NB*NH*SEQ = 131072
    int*   sel     = (int*)(scoresB + (long)NB * NH * SEQ);
    float* ksel    = (float*)(sel + NB * NH * TOPK);
    float* vsel    = ksel + (long)NB * NH * TOPK * HD;
    float* AO      = Vb;                        // attention output reuses V buffer

    dim3 blk(256);
    // projections
    gemm_nt<<<dim3(MDIM / 128, NDIM / 128), blk, 0, stream>>>(x, wq, Q,  NDIM, KDIM);
    gemm_nt<<<dim3(MDIM / 128, NDIM / 128), blk, 0, stream>>>(x, wk, Kb, NDIM, KDIM);
    gemm_nt<<<dim3(MDIM / 128, NDIM / 128), blk, 0, stream>>>(x, wv, Vb, NDIM, KDIM);
    // fused score net (no 64MB intermediate)
    scorenet<<<(MDIM * NH) / 128, blk, 0, stream>>>(Kb, sw1, sb1, sw2, sb2, scoresB);
    // exact top-128 set per (b,h)  (sparsek tau is a uniform shift -> same set)
    topk_sel<<<NB * NH, blk, 0, stream>>>(scoresB, sel);
    gather_kv<<<NB * NH * TOPK, 128, 0, stream>>>(Kb, Vb, sel, ksel, vsel);
    // attention over selected keys -> AO (overwrites V buffer, dead after gather)
    attention<<<dim3(NB * NH, SEQ / 32), blk, 0, stream>>>(Q, ksel, vsel, AO);
    // output projection
    gemm_nt<<<dim3(MDIM / 128, NDIM / 128), blk, 0, stream>>>(AO, wo, out, NDIM, KDIM);
}

// Round 3
// 1317.734 us; speedup vs baseline: 2.6473x; 2.6473x over previous
//
#include <hip/hip_runtime.h>

#define SEQ   4096
#define NB    2
#define NH    16
#define HD    128
#define TOPK  128
#define MDIM  (NB*SEQ)     // 8192
#define NDIM  2048
#define KDIM  2048

typedef unsigned short u16;
typedef __bf16  v8bf __attribute__((ext_vector_type(8)));
typedef float   v4f  __attribute__((ext_vector_type(4)));

__device__ __forceinline__ u16 f2b(float f) {               // fp32 -> bf16 RNE
    unsigned u = __float_as_uint(f);
    return (u16)((u + 0x7fffu + ((u >> 16) & 1u)) >> 16);
}
__device__ __forceinline__ float b2f(u16 h) {
    return __uint_as_float(((unsigned)h) << 16);
}

#define ASYNC16(gsrc, ldst) \
    __builtin_amdgcn_global_load_lds( \
        (const __attribute__((address_space(1))) unsigned int*)(gsrc), \
        (__attribute__((address_space(3))) unsigned int*)(ldst), 16, 0, 0)

// ---------------------------------------------------------------------------
// fp32 -> (bf16 hi, bf16 lo residual), 4 elems/thread
// ---------------------------------------------------------------------------
__global__ __launch_bounds__(256) void split_f32(const float* __restrict__ in,
                                                 u16* __restrict__ hi,
                                                 u16* __restrict__ lo, long n)
{
    long i = ((long)blockIdx.x * 256 + threadIdx.x) * 4;
    if (i >= n) return;
    float4 v = *(const float4*)(in + i);
    float vv[4] = {v.x, v.y, v.z, v.w};
    u16 h[4], l[4];
#pragma unroll
    for (int j = 0; j < 4; ++j) {
        h[j] = f2b(vv[j]);
        l[j] = f2b(vv[j] - b2f(h[j]));
    }
    uint2 ph, pl;
    ph.x = (unsigned)h[0] | ((unsigned)h[1] << 16);
    ph.y = (unsigned)h[2] | ((unsigned)h[3] << 16);
    pl.x = (unsigned)l[0] | ((unsigned)l[1] << 16);
    pl.y = (unsigned)l[2] | ((unsigned)l[3] << 16);
    *(uint2*)(hi + i) = ph;
    *(uint2*)(lo + i) = pl;
}

// fp32 -> bf16, 4 elems/thread
__global__ __launch_bounds__(256) void cvt_bf16(const float* __restrict__ in,
                                                u16* __restrict__ outb, long n)
{
    long i = ((long)blockIdx.x * 256 + threadIdx.x) * 4;
    if (i >= n) return;
    float4 v = *(const float4*)(in + i);
    uint2 p;
    p.x = (unsigned)f2b(v.x) | ((unsigned)f2b(v.y) << 16);
    p.y = (unsigned)f2b(v.z) | ((unsigned)f2b(v.w) << 16);
    *(uint2*)(outb + i) = p;
}

// ---------------------------------------------------------------------------
// MFMA bf16 GEMM (NT): C[M,2048] = A[M,2048](bf16) @ W[2048,2048](bf16)^T
// 128x128 tile, BK=32, 256 thr = 4 waves (2x2 of 64x64), 16 MFMA/K-step.
// mode: 0 = store fp32, 1 = accumulate fp32 (C +=), 2 = store bf16.
// ---------------------------------------------------------------------------
#define GM_STORE_F32 0
#define GM_ACC_F32   1
#define GM_STORE_B16 2

__global__ __launch_bounds__(256) void gemm_bf16_nt(const u16* __restrict__ A,
                                                    const u16* __restrict__ W,
                                                    float* __restrict__ Cf,
                                                    u16* __restrict__ Cb,
                                                    int mode)
{
    __shared__ __attribute__((aligned(16))) u16 As[128 * 32];
    __shared__ __attribute__((aligned(16))) u16 Ws[128 * 32];
    const int t  = threadIdx.x;
    const int bm = blockIdx.x, bn = blockIdx.y;

    // staging: thread covers 16B (8 bf16); rows t>>2 and 64+(t>>2)
    const u16* ag = A + (long)(bm * 128 + (t >> 2)) * KDIM + (t & 3) * 8;
    const u16* wg = W + (long)(bn * 128 + (t >> 2)) * KDIM + (t & 3) * 8;
    u16* la0 = As + t * 8;
    u16* la1 = As + 2048 + t * 8;   // rows 64..127
    u16* lw0 = Ws + t * 8;
    u16* lw1 = Ws + 2048 + t * 8;

    const int lane = t & 63, wid = t >> 6;
    const int wm = (wid >> 1) * 64, wn = (wid & 1) * 64;
    const int mr = lane & 15, q8 = (lane >> 4) * 8;

    v4f acc[4][4];
#pragma unroll
    for (int i = 0; i < 4; ++i)
#pragma unroll
        for (int j = 0; j < 4; ++j) {
            acc[i][j][0] = 0.f; acc[i][j][1] = 0.f;
            acc[i][j][2] = 0.f; acc[i][j][3] = 0.f;
        }

    for (int k0 = 0; k0 < KDIM; k0 += 32) {
        __syncthreads();                       // prior reads done before overwrite
        ASYNC16(ag + k0,             la0);
        ASYNC16(ag + k0 + 64 * KDIM, la1);
        ASYNC16(wg + k0,             lw0);
        ASYNC16(wg + k0 + 64 * KDIM, lw1);
        __syncthreads();                       // drains vmcnt -> tiles ready
        v8bf af[4], bw[4];
#pragma unroll
        for (int i = 0; i < 4; ++i) {
            af[i] = *(const v8bf*)&As[(wm + i * 16 + mr) * 32 + q8];
            bw[i] = *(const v8bf*)&Ws[(wn + i * 16 + mr) * 32 + q8];
        }
#pragma unroll
        for (int im = 0; im < 4; ++im)
#pragma unroll
            for (int in = 0; in < 4; ++in)
                acc[im][in] = __builtin_amdgcn_mfma_f32_16x16x32_bf16(
                                  af[im], bw[in], acc[im][in], 0, 0, 0);
    }

    // C/D layout: col = lane&15, row = (lane>>4)*4 + reg  [m89-verified]
    const int colb = bn * 128 + wn + mr;
    const int rowb = bm * 128 + wm + (lane >> 4) * 4;
#pragma unroll
    for (int im = 0; im < 4; ++im)
#pragma unroll
        for (int r = 0; r < 4; ++r) {
            long base = (long)(rowb + im * 16 + r) * NDIM + colb;
#pragma unroll
            for (int in = 0; in < 4; ++in) {
                float v = acc[im][in][r];
                long off = base + in * 16;
                if (mode == GM_STORE_F32)      Cf[off] = v;
                else if (mode == GM_ACC_F32)   Cf[off] += v;
                else                           Cb[off] = f2b(v);
            }
        }
}

// ---------------------------------------------------------------------------
// Fused score net on fp32 K: per 128-row tile of Kflat[131072][128],
// hidden = relu(Krows @ sw1^T + sb1) in regs, contract with sw2 -> scores.
// ---------------------------------------------------------------------------
__global__ __launch_bounds__(256) void scorenet(const float* __restrict__ Kb,
                                                const float* __restrict__ sw1,
                                                const float* __restrict__ sb1,
                                                const float* __restrict__ sw2,
                                                const float* __restrict__ sb2,
                                                float* __restrict__ scores)
{
    __shared__ float As[16][128];
    __shared__ float Bs[16][128];
    __shared__ float red[128][17];
    const int t  = threadIdx.x;
    const int tx = t & 15, ty = t >> 4;
    const int bm = blockIdx.x;
    const int lr = t >> 1;
    const int lc = (t & 1) * 8;
    const float* Ap = Kb + (long)(bm * 128 + lr) * HD + lc;
    const float* Wp = sw1 + lr * HD + lc;

    float acc[8][8];
#pragma unroll
    for (int i = 0; i < 8; ++i)
#pragma unroll
        for (int j = 0; j < 8; ++j) acc[i][j] = 0.f;

    for (int k0 = 0; k0 < HD; k0 += 16) {
        float4 a0 = *(const float4*)(Ap + k0);
        float4 a1 = *(const float4*)(Ap + k0 + 4);
        float4 b0 = *(const float4*)(Wp + k0);
        float4 b1 = *(const float4*)(Wp + k0 + 4);
        __syncthreads();
        As[lc+0][lr] = a0.x; As[lc+1][lr] = a0.y; As[lc+2][lr] = a0.z; As[lc+3][lr] = a0.w;
        As[lc+4][lr] = a1.x; As[lc+5][lr] = a1.y; As[lc+6][lr] = a1.z; As[lc+7][lr] = a1.w;
        Bs[lc+0][lr] = b0.x; Bs[lc+1][lr] = b0.y; Bs[lc+2][lr] = b0.z; Bs[lc+3][lr] = b0.w;
        Bs[lc+4][lr] = b1.x; Bs[lc+5][lr] = b1.y; Bs[lc+6][lr] = b1.z; Bs[lc+7][lr] = b1.w;
        __syncthreads();
#pragma unroll
        for (int kk = 0; kk < 16; ++kk) {
            float a[8], b[8];
            *(float4*)&a[0] = *(const float4*)&As[kk][ty * 8];
            *(float4*)&a[4] = *(const float4*)&As[kk][ty * 8 + 4];
            *(float4*)&b[0] = *(const float4*)&Bs[kk][tx * 8];
            *(float4*)&b[4] = *(const float4*)&Bs[kk][tx * 8 + 4];
#pragma unroll
            for (int i = 0; i < 8; ++i)
#pragma unroll
                for (int j = 0; j < 8; ++j)
                    acc[i][j] = fmaf(a[i], b[j], acc[i][j]);
        }
    }

    float b1v[8], w2v[8];
#pragma unroll
    for (int j = 0; j < 8; ++j) {
        b1v[j] = sb1[tx * 8 + j];
        w2v[j] = sw2[tx * 8 + j];
    }
#pragma unroll
    for (int i = 0; i < 8; ++i) {
        float p = 0.f;
#pragma unroll
        for (int j = 0; j < 8; ++j)
            p += fmaxf(acc[i][j] + b1v[j], 0.f) * w2v[j];
        red[ty * 8 + i][tx] = p;
    }
    __syncthreads();
    if (t < 128) {
        float s = sb2[0];
#pragma unroll
        for (int c = 0; c < 16; ++c) s += red[t][c];
        long r = (long)bm * 128 + t;               // r = (b*SEQ+s_idx)*NH + h
        int b  = (int)(r >> 16);
        int si = (int)((r >> 4) & (SEQ - 1));
        int h  = (int)(r & (NH - 1));
        scores[((b * NH + h) << 12) + si] = s;
    }
}

// ---------------------------------------------------------------------------
// Exact top-128 per (b,h) via radix select; ties -> lowest indices.
// ---------------------------------------------------------------------------
__global__ __launch_bounds__(256) void topk_sel(const float* __restrict__ scores,
                                                int* __restrict__ sel)
{
    __shared__ unsigned keys[SEQ];
    __shared__ unsigned hist[256];
    __shared__ int scal2[2];
    __shared__ unsigned cntG;
    __shared__ unsigned short tpre[256];
    const int t  = threadIdx.x;
    const int bh = blockIdx.x;
    const float* sc = scores + (long)bh * SEQ;
    for (int i = t; i < SEQ; i += 256) {
        unsigned u = __float_as_uint(sc[i]);
        u = (u & 0x80000000u) ? ~u : (u | 0x80000000u);
        keys[i] = u;
    }
    unsigned prefix = 0;
    int rem = TOPK;
    const int i0 = t * 16;
    for (int shift = 24; shift >= 0; shift -= 8) {
        hist[t] = 0;
        __syncthreads();
        const unsigned pm = (shift == 24) ? 0u : (0xFFFFFFFFu << (shift + 8));
        for (int i = i0; i < i0 + 16; ++i) {
            unsigned k = keys[i];
            if (((k ^ prefix) & pm) == 0) atomicAdd(&hist[(k >> shift) & 255], 1u);
        }
        __syncthreads();
        if (t == 0) {
            int r = rem, chosen = 0;
            for (int b = 255; b >= 0; --b) {
                int c = (int)hist[b];
                if (c >= r) { chosen = b; break; }
                r -= c;
            }
            scal2[0] = chosen; scal2[1] = r;
        }
        __syncthreads();
        prefix |= ((unsigned)scal2[0]) << shift;
        rem = scal2[1];
        __syncthreads();
    }
    if (t == 0) cntG = 0;
    __syncthreads();
    const unsigned T = prefix;
    int myT = 0;
    for (int i = i0; i < i0 + 16; ++i) {
        unsigned k = keys[i];
        if (k > T) {
            unsigned p = atomicAdd(&cntG, 1u);
            sel[bh * TOPK + p] = i;
        } else if (k == T) myT++;
    }
    tpre[t] = (unsigned short)myT;
    __syncthreads();
    if (t == 0) {
        unsigned s = 0;
        for (int i = 0; i < 256; ++i) { unsigned c = tpre[i]; tpre[i] = (unsigned short)s; s += c; }
    }
    __syncthreads();
    const int base = TOPK - rem;
    int rank = tpre[t];
    for (int i = i0; i < i0 + 16; ++i) {
        if (keys[i] == T) {
            if (rank < rem) sel[bh * TOPK + base + rank] = i;
            rank++;
        }
    }
}

// ---------------------------------------------------------------------------
// Gather selected rows: K (fp32) -> ksel fp32 ; V (bf16) -> vsel bf16
// ---------------------------------------------------------------------------
__global__ void gather_kv(const float* __restrict__ Kb, const u16* __restrict__ Vb,
                          const int* __restrict__ sel,
                          float* __restrict__ ks, u16* __restrict__ vs)
{
    int bh = blockIdx.x >> 7;
    int j  = blockIdx.x & 127;
    int d  = threadIdx.x;
    int s  = sel[bh * TOPK + j];
    int b = bh >> 4, h = bh & (NH - 1);
    long src = ((long)(b * SEQ + s)) * NDIM + h * HD + d;
    ks[((long)bh * TOPK + j) * HD + d] = Kb[src];
    vs[((long)bh * TOPK + j) * HD + d] = Vb[src];
}

// ---------------------------------------------------------------------------
// Attention over 128 selected keys. Q bf16, K fp32, V bf16, out bf16.
// ---------------------------------------------------------------------------
__global__ __launch_bounds__(256) void attention(const u16* __restrict__ Qb,
                                                 const float* __restrict__ ks,
                                                 const u16* __restrict__ vs,
                                                 u16* __restrict__ outp)
{
    __shared__ float qs[32][132];
    __shared__ float sc[32][132];
    __shared__ float kv[32][132];
    const int bh = blockIdx.x;
    const int qt = blockIdx.y;
    const int b = bh >> 4, h = bh & (NH - 1);
    const int t = threadIdx.x;
    const int q0 = qt * 32;
    const float scale = 0.08838834764831845f;   // 1/sqrt(128)

    const u16* qbase = Qb + ((long)(b * SEQ + q0)) * NDIM + h * HD;
    for (int f = t; f < 512; f += 256) {        // 8 bf16 -> 8 floats per iter
        int qi = f >> 4, c = (f & 15) * 8;
        uint4 raw = *(const uint4*)(qbase + (long)qi * NDIM + c);
        float* dst = &qs[qi][c];
        dst[0] = __uint_as_float(raw.x << 16); dst[1] = __uint_as_float(raw.x & 0xffff0000u);
        dst[2] = __uint_as_float(raw.y << 16); dst[3] = __uint_as_float(raw.y & 0xffff0000u);
        dst[4] = __uint_as_float(raw.z << 16); dst[5] = __uint_as_float(raw.z & 0xffff0000u);
        dst[6] = __uint_as_float(raw.w << 16); dst[7] = __uint_as_float(raw.w & 0xffff0000u);
    }
    const float* kbase = ks + (long)bh * TOPK * HD;
    const u16*   vbase = vs + (long)bh * TOPK * HD;
    const int kj = t & 31, qg = t >> 5;
    for (int ch = 0; ch < 4; ++ch) {
        __syncthreads();
        for (int f = t; f < 1024; f += 256) {
            int j = f >> 5, c = f & 31;
            *(float4*)&kv[j][c * 4] = *(const float4*)(kbase + (ch * 32 + j) * HD + c * 4);
        }
        __syncthreads();
        float a0 = 0.f, a1 = 0.f, a2 = 0.f, a3 = 0.f;
        for (int d4 = 0; d4 < 32; ++d4) {
            float4 kk4 = *(const float4*)&kv[kj][d4 * 4];
            float4 q0v = *(const float4*)&qs[qg * 4 + 0][d4 * 4];
            float4 q1v = *(const float4*)&qs[qg * 4 + 1][d4 * 4];
            float4 q2v = *(const float4*)&qs[qg * 4 + 2][d4 * 4];
            float4 q3v = *(const float4*)&qs[qg * 4 + 3][d4 * 4];
            a0 = fmaf(q0v.x, kk4.x, fmaf(q0v.y, kk4.y, fmaf(q0v.z, kk4.z, fmaf(q0v.w, kk4.w, a0))));
            a1 = fmaf(q1v.x, kk4.x, fmaf(q1v.y, kk4.y, fmaf(q1v.z, kk4.z, fmaf(q1v.w, kk4.w, a1))));
            a2 = fmaf(q2v.x, kk4.x, fmaf(q2v.y, kk4.y, fmaf(q2v.z, kk4.z, fmaf(q2v.w, kk4.w, a2))));
            a3 = fmaf(q3v.x, kk4.x, fmaf(q3v.y, kk4.y, fmaf(q3v.z, kk4.z, fmaf(q3v.w, kk4.w, a3))));
        }
        sc[qg * 4 + 0][ch * 32 + kj] = a0;
        sc[qg * 4 + 1][ch * 32 + kj] = a1;
        sc[qg * 4 + 2][ch * 32 + kj] = a2;
        sc[qg * 4 + 3][ch * 32 + kj] = a3;
    }
    __syncthreads();
    if (t < 32) {
        float mx = -1e30f;
        for (int j = 0; j < 128; ++j) mx = fmaxf(mx, sc[t][j]);
        float sum = 0.f;
        for (int j = 0; j < 128; ++j) {
            float e = __expf((sc[t][j] - mx) * scale);
            sc[t][j] = e; sum += e;
        }
        float inv = 1.f / sum;
        for (int j = 0; j < 128; ++j) sc[t][j] *= inv;
    }
    const int qi = t >> 3, dg = t & 7;
    float acc[16];
#pragma unroll
    for (int i = 0; i < 16; ++i) acc[i] = 0.f;
    for (int ch = 0; ch < 4; ++ch) {
        __syncthreads();
        for (int f = t; f < 512; f += 256) {
            int j = f >> 4, c = (f & 15) * 8;
            uint4 raw = *(const uint4*)(vbase + (long)(ch * 32 + j) * HD + c);
            float* dst = &kv[j][c];
            dst[0] = __uint_as_float(raw.x << 16); dst[1] = __uint_as_float(raw.x & 0xffff0000u);
            dst[2] = __uint_as_float(raw.y << 16); dst[3] = __uint_as_float(raw.y & 0xffff0000u);
            dst[4] = __uint_as_float(raw.z << 16); dst[5] = __uint_as_float(raw.z & 0xffff0000u);
            dst[6] = __uint_as_float(raw.w << 16); dst[7] = __uint_as_float(raw.w & 0xffff0000u);
        }
        __syncthreads();
        for (int j = 0; j < 32; ++j) {
            float a = sc[qi][ch * 32 + j];
#pragma unroll
            for (int i4 = 0; i4 < 4; ++i4) {
                float4 vv = *(const float4*)&kv[j][dg * 16 + i4 * 4];
                acc[i4 * 4 + 0] = fmaf(a, vv.x, acc[i4 * 4 + 0]);
                acc[i4 * 4 + 1] = fmaf(a, vv.y, acc[i4 * 4 + 1]);
                acc[i4 * 4 + 2] = fmaf(a, vv.z, acc[i4 * 4 + 2]);
                acc[i4 * 4 + 3] = fmaf(a, vv.w, acc[i4 * 4 + 3]);
            }
        }
    }
    u16* o = outp + ((long)(b * SEQ + q0 + qi)) * NDIM + h * HD + dg * 16;
    unsigned pk[8];
#pragma unroll
    for (int i = 0; i < 8; ++i)
        pk[i] = (unsigned)f2b(acc[2 * i]) | ((unsigned)f2b(acc[2 * i + 1]) << 16);
    *(uint4*)o       = make_uint4(pk[0], pk[1], pk[2], pk[3]);
    *(uint4*)(o + 8) = make_uint4(pk[4], pk[5], pk[6], pk[7]);
}

// ---------------------------------------------------------------------------
extern "C" void kernel_launch(void* const* d_in, const int* in_sizes, int n_in,
                              void* d_out, int out_size, void* d_ws, size_t ws_size,
                              hipStream_t stream)
{
    const float* x   = (const float*)d_in[0];
    const float* wq  = (const float*)d_in[1];
    const float* wk  = (const float*)d_in[2];
    const float* wv  = (const float*)d_in[3];
    const float* wo  = (const float*)d_in[4];
    const float* sw1 = (const float*)d_in[5];
    const float* sb1 = (const float*)d_in[6];
    const float* sw2 = (const float*)d_in[7];
    const float* sb2 = (const float*)d_in[8];
    float* out = (float*)d_out;

    // workspace layout (bytes), total 188,235,776 B = 179.5 MiB
    char* base = (char*)d_ws;
    u16*   xh      = (u16*)  base;                     // 33,554,432
    u16*   xl      = (u16*) (base + 33554432L);        // 33,554,432 (later: Qb)
    float* Kf      = (float*)(base + 67108864L);       // 67,108,864
    u16*   Vb      = (u16*) (base + 134217728L);       // 33,554,432 (later: AOb)
    u16*   W1      = (u16*) (base + 167772160L);       // 8,388,608
    u16*   W2      = (u16*) (base + 176160768L);       // 8,388,608
    float* scoresB = (float*)(base + 184549376L);      // 524,288
    int*   sel     = (int*) (base + 185073664L);       // 16,384
    float* ksel    = (float*)(base + 185090048L);      // 2,097,152
    u16*   vsel    = (u16*) (base + 187187200L);       // 1,048,576
    u16*   Qb      = xl;                               // alias: xl dead after K passes
    u16*   AOb     = Vb;                               // alias: Vb dead after gather

    const long NX = (long)MDIM * NDIM;   // 16,777,216
    const long NW = (long)NDIM * KDIM / 2 * 2;  // 4,194,304 per weight? (2048*2048)
    dim3 blk(256);
    dim3 gg(MDIM / 128, NDIM / 128);     // (64,16)

    // precision splits / casts
    split_f32<<<16384, blk, 0, stream>>>(x,  xh, xl, NX);
    split_f32<<<4096,  blk, 0, stream>>>(wk, W1, W2, (long)NDIM * KDIM);
    // K = xh@wkh^T + xh@wkl^T + xl@wkh^T  (fp32-accurate K for selection path)
    gemm_bf16_nt<<<gg, blk, 0, stream>>>(xh, W1, Kf, nullptr, GM_STORE_F32);
    gemm_bf16_nt<<<gg, blk, 0, stream>>>(xh, W2, Kf, nullptr, GM_ACC_F32);
    gemm_bf16_nt<<<gg, blk, 0, stream>>>(xl, W1, Kf, nullptr, GM_ACC_F32);
    // Q, V in plain bf16 (W slots reused)
    cvt_bf16<<<4096, blk, 0, stream>>>(wq, W1, (long)NDIM * KDIM);
    cvt_bf16<<<4096, blk, 0, stream>>>(wv, W2, (long)NDIM * KDIM);
    gemm_bf16_nt<<<gg, blk, 0, stream>>>(xh, W1, nullptr, Qb, GM_STORE_B16);
    gemm_bf16_nt<<<gg, blk, 0, stream>>>(xh, W2, nullptr, Vb, GM_STORE_B16);
    // score net on fp32 K -> exact selection
    scorenet<<<(MDIM * NH) / 128, blk, 0, stream>>>(Kf, sw1, sb1, sw2, sb2, scoresB);
    topk_sel<<<NB * NH, blk, 0, stream>>>(scoresB, sel);
    gather_kv<<<NB * NH * TOPK, 128, 0, stream>>>(Kf, Vb, sel, ksel, vsel);
    attention<<<dim3(NB * NH, SEQ / 32), blk, 0, stream>>>(Qb, ksel, vsel, AOb);
    // output projection
    cvt_bf16<<<4096, blk, 0, stream>>>(wo, W1, (long)NDIM * KDIM);
    gemm_bf16_nt<<<gg, blk, 0, stream>>>(AOb, W1, out, nullptr, GM_STORE_F32);
}

// Round 4
// 1052.724 us; speedup vs baseline: 3.3137x; 1.2517x over previous
//
#include <hip/hip_runtime.h>

#define SEQ   4096
#define NB    2
#define NH    16
#define HD    128
#define TOPK  128
#define MDIM  (NB*SEQ)     // 8192
#define NDIM  2048
#define KDIM  2048

typedef unsigned short u16;
typedef __bf16  v8bf __attribute__((ext_vector_type(8)));
typedef float   v4f  __attribute__((ext_vector_type(4)));

__device__ __forceinline__ u16 f2b(float f) {               // fp32 -> bf16 RNE
    unsigned u = __float_as_uint(f);
    return (u16)((u + 0x7fffu + ((u >> 16) & 1u)) >> 16);
}
__device__ __forceinline__ float b2f(u16 h) {
    return __uint_as_float(((unsigned)h) << 16);
}

#define ASYNC16(gsrc, ldst) \
    __builtin_amdgcn_global_load_lds( \
        (const __attribute__((address_space(1))) unsigned int*)(gsrc), \
        (__attribute__((address_space(3))) unsigned int*)(ldst), 16, 0, 0)

// ---------------------------------------------------------------------------
// fp32 -> (bf16 hi, bf16 lo residual), 4 elems/thread
// ---------------------------------------------------------------------------
__global__ __launch_bounds__(256) void split_f32(const float* __restrict__ in,
                                                 u16* __restrict__ hi,
                                                 u16* __restrict__ lo, long n)
{
    long i = ((long)blockIdx.x * 256 + threadIdx.x) * 4;
    if (i >= n) return;
    float4 v = *(const float4*)(in + i);
    float vv[4] = {v.x, v.y, v.z, v.w};
    u16 h[4], l[4];
#pragma unroll
    for (int j = 0; j < 4; ++j) {
        h[j] = f2b(vv[j]);
        l[j] = f2b(vv[j] - b2f(h[j]));
    }
    uint2 ph, pl;
    ph.x = (unsigned)h[0] | ((unsigned)h[1] << 16);
    ph.y = (unsigned)h[2] | ((unsigned)h[3] << 16);
    pl.x = (unsigned)l[0] | ((unsigned)l[1] << 16);
    pl.y = (unsigned)l[2] | ((unsigned)l[3] << 16);
    *(uint2*)(hi + i) = ph;
    *(uint2*)(lo + i) = pl;
}

// fp32 -> bf16, 4 elems/thread
__global__ __launch_bounds__(256) void cvt_bf16(const float* __restrict__ in,
                                                u16* __restrict__ outb, long n)
{
    long i = ((long)blockIdx.x * 256 + threadIdx.x) * 4;
    if (i >= n) return;
    float4 v = *(const float4*)(in + i);
    uint2 p;
    p.x = (unsigned)f2b(v.x) | ((unsigned)f2b(v.y) << 16);
    p.y = (unsigned)f2b(v.z) | ((unsigned)f2b(v.w) << 16);
    *(uint2*)(outb + i) = p;
}

// ---------------------------------------------------------------------------
// MFMA bf16 GEMM (NT): C[M,2048] = A[M,2048](bf16) @ W[2048,2048](bf16)^T
// 128x128 tile, BK=32, 256 thr = 4 waves (2x2 of 64x64), 16 MFMA/K-step.
// ---------------------------------------------------------------------------
#define GM_STORE_F32 0
#define GM_ACC_F32   1
#define GM_STORE_B16 2

__global__ __launch_bounds__(256) void gemm_bf16_nt(const u16* __restrict__ A,
                                                    const u16* __restrict__ W,
                                                    float* __restrict__ Cf,
                                                    u16* __restrict__ Cb,
                                                    int mode)
{
    __shared__ __attribute__((aligned(16))) u16 As[128 * 32];
    __shared__ __attribute__((aligned(16))) u16 Ws[128 * 32];
    const int t  = threadIdx.x;
    const int bm = blockIdx.x, bn = blockIdx.y;

    const u16* ag = A + (long)(bm * 128 + (t >> 2)) * KDIM + (t & 3) * 8;
    const u16* wg = W + (long)(bn * 128 + (t >> 2)) * KDIM + (t & 3) * 8;
    u16* la0 = As + t * 8;
    u16* la1 = As + 2048 + t * 8;   // rows 64..127
    u16* lw0 = Ws + t * 8;
    u16* lw1 = Ws + 2048 + t * 8;

    const int lane = t & 63, wid = t >> 6;
    const int wm = (wid >> 1) * 64, wn = (wid & 1) * 64;
    const int mr = lane & 15, q8 = (lane >> 4) * 8;

    v4f acc[4][4];
#pragma unroll
    for (int i = 0; i < 4; ++i)
#pragma unroll
        for (int j = 0; j < 4; ++j) {
            acc[i][j][0] = 0.f; acc[i][j][1] = 0.f;
            acc[i][j][2] = 0.f; acc[i][j][3] = 0.f;
        }

    for (int k0 = 0; k0 < KDIM; k0 += 32) {
        __syncthreads();
        ASYNC16(ag + k0,             la0);
        ASYNC16(ag + k0 + 64 * KDIM, la1);
        ASYNC16(wg + k0,             lw0);
        ASYNC16(wg + k0 + 64 * KDIM, lw1);
        __syncthreads();
        v8bf af[4], bw[4];
#pragma unroll
        for (int i = 0; i < 4; ++i) {
            af[i] = *(const v8bf*)&As[(wm + i * 16 + mr) * 32 + q8];
            bw[i] = *(const v8bf*)&Ws[(wn + i * 16 + mr) * 32 + q8];
        }
#pragma unroll
        for (int im = 0; im < 4; ++im)
#pragma unroll
            for (int in = 0; in < 4; ++in)
                acc[im][in] = __builtin_amdgcn_mfma_f32_16x16x32_bf16(
                                  af[im], bw[in], acc[im][in], 0, 0, 0);
    }

    const int colb = bn * 128 + wn + mr;
    const int rowb = bm * 128 + wm + (lane >> 4) * 4;
#pragma unroll
    for (int im = 0; im < 4; ++im)
#pragma unroll
        for (int r = 0; r < 4; ++r) {
            long base = (long)(rowb + im * 16 + r) * NDIM + colb;
#pragma unroll
            for (int in = 0; in < 4; ++in) {
                float v = acc[im][in][r];
                long off = base + in * 16;
                if (mode == GM_STORE_F32)      Cf[off] = v;
                else if (mode == GM_ACC_F32)   Cf[off] += v;
                else                           Cb[off] = f2b(v);
            }
        }
}

// ---------------------------------------------------------------------------
// Fused score net on fp32 K (selection-critical, stays fp32 VALU)
// ---------------------------------------------------------------------------
__global__ __launch_bounds__(256) void scorenet(const float* __restrict__ Kb,
                                                const float* __restrict__ sw1,
                                                const float* __restrict__ sb1,
                                                const float* __restrict__ sw2,
                                                const float* __restrict__ sb2,
                                                float* __restrict__ scores)
{
    __shared__ float As[16][128];
    __shared__ float Bs[16][128];
    __shared__ float red[128][17];
    const int t  = threadIdx.x;
    const int tx = t & 15, ty = t >> 4;
    const int bm = blockIdx.x;
    const int lr = t >> 1;
    const int lc = (t & 1) * 8;
    const float* Ap = Kb + (long)(bm * 128 + lr) * HD + lc;
    const float* Wp = sw1 + lr * HD + lc;

    float acc[8][8];
#pragma unroll
    for (int i = 0; i < 8; ++i)
#pragma unroll
        for (int j = 0; j < 8; ++j) acc[i][j] = 0.f;

    for (int k0 = 0; k0 < HD; k0 += 16) {
        float4 a0 = *(const float4*)(Ap + k0);
        float4 a1 = *(const float4*)(Ap + k0 + 4);
        float4 b0 = *(const float4*)(Wp + k0);
        float4 b1 = *(const float4*)(Wp + k0 + 4);
        __syncthreads();
        As[lc+0][lr] = a0.x; As[lc+1][lr] = a0.y; As[lc+2][lr] = a0.z; As[lc+3][lr] = a0.w;
        As[lc+4][lr] = a1.x; As[lc+5][lr] = a1.y; As[lc+6][lr] = a1.z; As[lc+7][lr] = a1.w;
        Bs[lc+0][lr] = b0.x; Bs[lc+1][lr] = b0.y; Bs[lc+2][lr] = b0.z; Bs[lc+3][lr] = b0.w;
        Bs[lc+4][lr] = b1.x; Bs[lc+5][lr] = b1.y; Bs[lc+6][lr] = b1.z; Bs[lc+7][lr] = b1.w;
        __syncthreads();
#pragma unroll
        for (int kk = 0; kk < 16; ++kk) {
            float a[8], b[8];
            *(float4*)&a[0] = *(const float4*)&As[kk][ty * 8];
            *(float4*)&a[4] = *(const float4*)&As[kk][ty * 8 + 4];
            *(float4*)&b[0] = *(const float4*)&Bs[kk][tx * 8];
            *(float4*)&b[4] = *(const float4*)&Bs[kk][tx * 8 + 4];
#pragma unroll
            for (int i = 0; i < 8; ++i)
#pragma unroll
                for (int j = 0; j < 8; ++j)
                    acc[i][j] = fmaf(a[i], b[j], acc[i][j]);
        }
    }

    float b1v[8], w2v[8];
#pragma unroll
    for (int j = 0; j < 8; ++j) {
        b1v[j] = sb1[tx * 8 + j];
        w2v[j] = sw2[tx * 8 + j];
    }
#pragma unroll
    for (int i = 0; i < 8; ++i) {
        float p = 0.f;
#pragma unroll
        for (int j = 0; j < 8; ++j)
            p += fmaxf(acc[i][j] + b1v[j], 0.f) * w2v[j];
        red[ty * 8 + i][tx] = p;
    }
    __syncthreads();
    if (t < 128) {
        float s = sb2[0];
#pragma unroll
        for (int c = 0; c < 16; ++c) s += red[t][c];
        long r = (long)bm * 128 + t;
        int b  = (int)(r >> 16);
        int si = (int)((r >> 4) & (SEQ - 1));
        int h  = (int)(r & (NH - 1));
        scores[((b * NH + h) << 12) + si] = s;
    }
}

// ---------------------------------------------------------------------------
// Exact top-128 per (b,h) via radix select; ties -> lowest indices.
// ---------------------------------------------------------------------------
__global__ __launch_bounds__(256) void topk_sel(const float* __restrict__ scores,
                                                int* __restrict__ sel)
{
    __shared__ unsigned keys[SEQ];
    __shared__ unsigned hist[256];
    __shared__ int scal2[2];
    __shared__ unsigned cntG;
    __shared__ unsigned short tpre[256];
    const int t  = threadIdx.x;
    const int bh = blockIdx.x;
    const float* sc = scores + (long)bh * SEQ;
    for (int i = t; i < SEQ; i += 256) {
        unsigned u = __float_as_uint(sc[i]);
        u = (u & 0x80000000u) ? ~u : (u | 0x80000000u);
        keys[i] = u;
    }
    unsigned prefix = 0;
    int rem = TOPK;
    const int i0 = t * 16;
    for (int shift = 24; shift >= 0; shift -= 8) {
        hist[t] = 0;
        __syncthreads();
        const unsigned pm = (shift == 24) ? 0u : (0xFFFFFFFFu << (shift + 8));
        for (int i = i0; i < i0 + 16; ++i) {
            unsigned k = keys[i];
            if (((k ^ prefix) & pm) == 0) atomicAdd(&hist[(k >> shift) & 255], 1u);
        }
        __syncthreads();
        if (t == 0) {
            int r = rem, chosen = 0;
            for (int b = 255; b >= 0; --b) {
                int c = (int)hist[b];
                if (c >= r) { chosen = b; break; }
                r -= c;
            }
            scal2[0] = chosen; scal2[1] = r;
        }
        __syncthreads();
        prefix |= ((unsigned)scal2[0]) << shift;
        rem = scal2[1];
        __syncthreads();
    }
    if (t == 0) cntG = 0;
    __syncthreads();
    const unsigned T = prefix;
    int myT = 0;
    for (int i = i0; i < i0 + 16; ++i) {
        unsigned k = keys[i];
        if (k > T) {
            unsigned p = atomicAdd(&cntG, 1u);
            sel[bh * TOPK + p] = i;
        } else if (k == T) myT++;
    }
    tpre[t] = (unsigned short)myT;
    __syncthreads();
    if (t == 0) {
        unsigned s = 0;
        for (int i = 0; i < 256; ++i) { unsigned c = tpre[i]; tpre[i] = (unsigned short)s; s += c; }
    }
    __syncthreads();
    const int base = TOPK - rem;
    int rank = tpre[t];
    for (int i = i0; i < i0 + 16; ++i) {
        if (keys[i] == T) {
            if (rank < rem) sel[bh * TOPK + base + rank] = i;
            rank++;
        }
    }
}

// ---------------------------------------------------------------------------
// Gather: K (fp32) -> ksb bf16 [bh][key][d] ; V (bf16) -> vsT bf16 [bh][d][key]
// ---------------------------------------------------------------------------
__global__ void gather_kv(const float* __restrict__ Kf, const u16* __restrict__ Vb,
                          const int* __restrict__ sel,
                          u16* __restrict__ ksb, u16* __restrict__ vsT)
{
    int bh = blockIdx.x >> 7;
    int j  = blockIdx.x & 127;
    int d  = threadIdx.x;
    int s  = sel[bh * TOPK + j];
    int b = bh >> 4, h = bh & (NH - 1);
    long src = ((long)(b * SEQ + s)) * NDIM + h * HD + d;
    ksb[((long)bh * TOPK + j) * HD + d] = f2b(Kf[src]);
    vsT[((long)bh * HD + d) * TOPK + j] = Vb[src];
}

// ---------------------------------------------------------------------------
// MFMA attention: block = 128 queries of one (b,h), 4 waves x 32 queries.
// QK^T in registers (K B-frags from L2-hot ksb), softmax via shfl_xor,
// P through XOR-swizzled LDS (C-layout -> A-layout), PV with vsT B-frags,
// O bounced through LDS for coalesced 16B stores.
// ---------------------------------------------------------------------------
__device__ __forceinline__ int paddr(int row, int col) {   // u16 index into P
    int chunk = (col >> 3) ^ (row & 15);
    return row * 128 + chunk * 8 + (col & 7);
}

__global__ __launch_bounds__(256) void attn_mfma(const u16* __restrict__ Qb,
                                                 const u16* __restrict__ ksb,
                                                 const u16* __restrict__ vsT,
                                                 u16* __restrict__ outp)
{
    __shared__ __attribute__((aligned(16))) u16 P[128 * 128];  // 32 KB
    const int bh = blockIdx.x, qt = blockIdx.y;
    const int b = bh >> 4, h = bh & (NH - 1);
    const int t = threadIdx.x, lane = t & 63, w = t >> 6;
    const int mr = lane & 15, q4 = lane >> 4;
    const float scale = 0.08838834764831845f;   // 1/sqrt(128)

    // Q A-fragments: 2 m-tiles x 4 k-steps (A[m=lane&15][k=quad*8+j])
    const u16* q0p = Qb + ((long)(b * SEQ + qt * 128 + w * 32 + mr)) * NDIM
                        + h * HD + q4 * 8;
    v8bf aq[2][4];
#pragma unroll
    for (int ks = 0; ks < 4; ++ks) {
        aq[0][ks] = *(const v8bf*)(q0p + ks * 32);
        aq[1][ks] = *(const v8bf*)(q0p + 16 * NDIM + ks * 32);
    }

    // S = Q @ Ksel^T  (n-tiles = 8 key tiles of 16)
    const u16* kbase = ksb + (long)bh * TOPK * HD + mr * HD + q4 * 8;
    v4f acc[2][8];
#pragma unroll
    for (int i = 0; i < 2; ++i)
#pragma unroll
        for (int j = 0; j < 8; ++j) {
            acc[i][j][0] = 0.f; acc[i][j][1] = 0.f;
            acc[i][j][2] = 0.f; acc[i][j][3] = 0.f;
        }
#pragma unroll
    for (int ks = 0; ks < 4; ++ks) {
        v8bf bk[8];
#pragma unroll
        for (int nt = 0; nt < 8; ++nt)
            bk[nt] = *(const v8bf*)(kbase + (long)nt * 16 * HD + ks * 32);
#pragma unroll
        for (int mt = 0; mt < 2; ++mt)
#pragma unroll
            for (int nt = 0; nt < 8; ++nt)
                acc[mt][nt] = __builtin_amdgcn_mfma_f32_16x16x32_bf16(
                                  aq[mt][ks], bk[nt], acc[mt][nt], 0, 0, 0);
    }

    // softmax per query row (C-layout: row = quad*4+reg, col = nt*16 + mr)
#pragma unroll
    for (int mt = 0; mt < 2; ++mt)
#pragma unroll
        for (int r = 0; r < 4; ++r) {
            float mx = acc[mt][0][r];
#pragma unroll
            for (int nt = 1; nt < 8; ++nt) mx = fmaxf(mx, acc[mt][nt][r]);
#pragma unroll
            for (int m = 1; m < 16; m <<= 1) mx = fmaxf(mx, __shfl_xor(mx, m));
            float sum = 0.f;
#pragma unroll
            for (int nt = 0; nt < 8; ++nt) {
                float e = __expf((acc[mt][nt][r] - mx) * scale);
                acc[mt][nt][r] = e; sum += e;
            }
#pragma unroll
            for (int m = 1; m < 16; m <<= 1) sum += __shfl_xor(sum, m);
            float inv = 1.f / sum;
#pragma unroll
            for (int nt = 0; nt < 8; ++nt) acc[mt][nt][r] *= inv;
        }

    // P -> LDS (swizzled), C-layout write
#pragma unroll
    for (int mt = 0; mt < 2; ++mt)
#pragma unroll
        for (int nt = 0; nt < 8; ++nt)
#pragma unroll
            for (int r = 0; r < 4; ++r)
                P[paddr(w * 32 + mt * 16 + q4 * 4 + r, nt * 16 + mr)] =
                    f2b(acc[mt][nt][r]);
    __syncthreads();

    // O = P @ Vsel   (B from vsT[d][key]: n = d, k = key)
    const u16* vbase = vsT + (long)bh * HD * TOPK + mr * TOPK + q4 * 8;
    v4f acc2[2][8];
#pragma unroll
    for (int i = 0; i < 2; ++i)
#pragma unroll
        for (int j = 0; j < 8; ++j) {
            acc2[i][j][0] = 0.f; acc2[i][j][1] = 0.f;
            acc2[i][j][2] = 0.f; acc2[i][j][3] = 0.f;
        }
#pragma unroll
    for (int ks = 0; ks < 4; ++ks) {
        v8bf ap[2];
        ap[0] = *(const v8bf*)&P[paddr(w * 32 + mr,      ks * 32 + q4 * 8)];
        ap[1] = *(const v8bf*)&P[paddr(w * 32 + 16 + mr, ks * 32 + q4 * 8)];
        v8bf bv[8];
#pragma unroll
        for (int nt = 0; nt < 8; ++nt)
            bv[nt] = *(const v8bf*)(vbase + (long)nt * 16 * TOPK + ks * 32);
#pragma unroll
        for (int mt = 0; mt < 2; ++mt)
#pragma unroll
            for (int nt = 0; nt < 8; ++nt)
                acc2[mt][nt] = __builtin_amdgcn_mfma_f32_16x16x32_bf16(
                                   ap[mt], bv[nt], acc2[mt][nt], 0, 0, 0);
    }
    __syncthreads();   // all P reads complete before overwriting with O

    // O -> LDS (swizzled), then coalesced global store
#pragma unroll
    for (int mt = 0; mt < 2; ++mt)
#pragma unroll
        for (int nt = 0; nt < 8; ++nt)
#pragma unroll
            for (int r = 0; r < 4; ++r)
                P[paddr(w * 32 + mt * 16 + q4 * 4 + r, nt * 16 + mr)] =
                    f2b(acc2[mt][nt][r]);
    __syncthreads();

    u16* obase = outp + ((long)(b * SEQ + qt * 128)) * NDIM + h * HD;
    for (int f = t; f < 2048; f += 256) {      // 128 rows x 16 chunks of 16B
        int row = f >> 4, cc = f & 15;
        uint4 val = *(const uint4*)&P[row * 128 + (cc ^ (row & 15)) * 8];
        *(uint4*)(obase + (long)row * NDIM + cc * 8) = val;
    }
}

// ---------------------------------------------------------------------------
extern "C" void kernel_launch(void* const* d_in, const int* in_sizes, int n_in,
                              void* d_out, int out_size, void* d_ws, size_t ws_size,
                              hipStream_t stream)
{
    const float* x   = (const float*)d_in[0];
    const float* wq  = (const float*)d_in[1];
    const float* wk  = (const float*)d_in[2];
    const float* wv  = (const float*)d_in[3];
    const float* wo  = (const float*)d_in[4];
    const float* sw1 = (const float*)d_in[5];
    const float* sb1 = (const float*)d_in[6];
    const float* sw2 = (const float*)d_in[7];
    const float* sb2 = (const float*)d_in[8];
    float* out = (float*)d_out;

    // workspace layout (bytes), ~179.5 MiB total
    char* base = (char*)d_ws;
    u16*   xh      = (u16*)  base;                     // 33,554,432
    u16*   xl      = (u16*) (base + 33554432L);        // 33,554,432 (later: Qb)
    float* Kf      = (float*)(base + 67108864L);       // 67,108,864
    u16*   Vb      = (u16*) (base + 134217728L);       // 33,554,432 (later: AOb)
    u16*   W1      = (u16*) (base + 167772160L);       // 8,388,608
    u16*   W2      = (u16*) (base + 176160768L);       // 8,388,608
    float* scoresB = (float*)(base + 184549376L);      // 524,288
    int*   sel     = (int*) (base + 185073664L);       // 16,384
    u16*   ksb     = (u16*) (base + 185090048L);       // 1,048,576
    u16*   vsT     = (u16*) (base + 186138624L);       // 1,048,576
    u16*   Qb      = xl;                               // alias: xl dead after K passes
    u16*   AOb     = Vb;                               // alias: Vb dead after gather

    const long NX = (long)MDIM * NDIM;
    dim3 blk(256);
    dim3 gg(MDIM / 128, NDIM / 128);

    // precision splits / casts
    split_f32<<<16384, blk, 0, stream>>>(x,  xh, xl, NX);
    split_f32<<<4096,  blk, 0, stream>>>(wk, W1, W2, (long)NDIM * KDIM);
    // K = xh@wkh^T + xh@wkl^T + xl@wkh^T  (fp32-accurate K for selection)
    gemm_bf16_nt<<<gg, blk, 0, stream>>>(xh, W1, Kf, nullptr, GM_STORE_F32);
    gemm_bf16_nt<<<gg, blk, 0, stream>>>(xh, W2, Kf, nullptr, GM_ACC_F32);
    gemm_bf16_nt<<<gg, blk, 0, stream>>>(xl, W1, Kf, nullptr, GM_ACC_F32);
    // Q, V in plain bf16
    cvt_bf16<<<4096, blk, 0, stream>>>(wq, W1, (long)NDIM * KDIM);
    cvt_bf16<<<4096, blk, 0, stream>>>(wv, W2, (long)NDIM * KDIM);
    gemm_bf16_nt<<<gg, blk, 0, stream>>>(xh, W1, nullptr, Qb, GM_STORE_B16);
    gemm_bf16_nt<<<gg, blk, 0, stream>>>(xh, W2, nullptr, Vb, GM_STORE_B16);
    // selection path (fp32 K)
    scorenet<<<(MDIM * NH) / 128, blk, 0, stream>>>(Kf, sw1, sb1, sw2, sb2, scoresB);
    topk_sel<<<NB * NH, blk, 0, stream>>>(scoresB, sel);
    gather_kv<<<NB * NH * TOPK, 128, 0, stream>>>(Kf, Vb, sel, ksb, vsT);
    // MFMA attention -> AOb
    attn_mfma<<<dim3(NB * NH, SEQ / 128), blk, 0, stream>>>(Qb, ksb, vsT, AOb);
    // output projection
    cvt_bf16<<<4096, blk, 0, stream>>>(wo, W1, (long)NDIM * KDIM);
    gemm_bf16_nt<<<gg, blk, 0, stream>>>(AOb, W1, out, nullptr, GM_STORE_F32);
}